// Round 19
// baseline (206.496 us; speedup 1.0000x reference)
//
#include <hip/hip_runtime.h>
#include <hip/hip_bf16.h>
#include <math.h>

typedef __attribute__((ext_vector_type(8))) short short8;   // 8 bf16 = one MFMA A/B frag
typedef __attribute__((ext_vector_type(4))) float f32x4;    // MFMA C/D frag

#define MFMA16x16x32(A,B,C) __builtin_amdgcn_mfma_f32_16x16x32_bf16((A),(B),(C),0,0,0)
#define LGKM0()   asm volatile("s_waitcnt lgkmcnt(0)" ::: "memory")
// barrier that does NOT drain vmcnt (keeps B/A register prefetches in flight)
#define BAR_LGKM() do { LGKM0(); __builtin_amdgcn_s_barrier(); } while (0)

__device__ __forceinline__ short f2b(float x) {
  __hip_bfloat16 h = __float2bfloat16(x);
  short s; __builtin_memcpy(&s, &h, 2); return s;
}
__device__ __forceinline__ float b2f(short s) {
  __hip_bfloat16 h; __builtin_memcpy(&h, &s, 2); return __bfloat162float(h);
}

// ---------------------------------------------------------------------------
// prep: blocks 0..63 pack the 4 weights [512][512] fp32 -> bf16 MFMA B-frag
// order: elem index = ((kf*32 + nf)*64 + lane)*8 + jj, where lane holds
// (n = nf*16 + lane%16, k = kf*32 + 8*(lane/16) + jj). block 64: softplus(scale).
// ---------------------------------------------------------------------------
__global__ __launch_bounds__(256)
void prep_kernel(const float* __restrict__ Wq, const float* __restrict__ Wk,
                 const float* __restrict__ Wv, const float* __restrict__ Wp,
                 const float* __restrict__ scale,
                 short* __restrict__ wpack, float* __restrict__ spls)
{
  const int b = blockIdx.x;
  const int t = threadIdx.x;
  if (b == 64) {
    for (int i = t; i < 512; i += 256) {
      float x = scale[i];
      spls[i] = (x > 20.f) ? x : log1pf(expf(x));
    }
    return;
  }
  const float* Ws[4] = {Wq, Wk, Wv, Wp};
  const int w = b >> 4, kf16 = b & 15;
  const float* W = Ws[w];
  short* dst = wpack + (size_t)w * (512 * 512);
  __shared__ short lds[32 * 512];
  for (int i = 0; i < 64; ++i) {
    int idx = i * 256 + t;              // 0..16383
    int r = idx >> 9, c = idx & 511;
    lds[idx] = f2b(W[(size_t)(kf16 * 32 + r) * 512 + c]);
  }
  __syncthreads();
  for (int s = 0; s < 8; ++s) {
    int slot = s * 256 + t;             // 0..2047 = 32 nfrags x 64 lanes
    int nf = slot >> 6, l = slot & 63;
    int n = nf * 16 + (l & 15);
    int k0 = 8 * (l >> 4);
    short8 v;
#pragma unroll
    for (int jj = 0; jj < 8; ++jj) v[jj] = lds[(k0 + jj) * 512 + n];
    *(short8*)(dst + ((size_t)(kf16 * 32 + nf) * 64 + l) * 8) = v;
  }
}

// ---------------------------------------------------------------------------
// proj (r18 best): fused q/k/v, 64 rows x 512 cols, 8 waves, 4x4 acc,
// A-slice dbuf BK=128 padded LDS, 2-deep rotating B reg prefetch, per-block
// kf phase rotation, lgkm-only barriers, mode=bid%3 interleave, setprio.
// mode 0: q -> relu,+eps,/s,focus -> row-major bf16.
// mode 1: k -> same epilogue -> k-major frag pack. mode 2: v -> plain pack.
// ---------------------------------------------------------------------------
__global__ __launch_bounds__(512, 2)
void proj_kernel(const float* __restrict__ Aq, const float* __restrict__ Ak,
                 const float* __restrict__ Av,
                 const short* __restrict__ wpack, const float* __restrict__ spls,
                 short* __restrict__ qf, short* __restrict__ kpk,
                 short* __restrict__ vpk)
{
  __shared__ char smem[65536];          // A-slice dbuf (2x17408B) / 64KB bounce
  __shared__ float pnorm[2][8][64];     // per-wave row-norm partials
  __shared__ float facs[64];
  short* tile = (short*)smem;
  const int t = threadIdx.x;
  const int lane = t & 63;
  const int wid = t >> 6;               // wave owns cols [wid*64, wid*64+64)
  const int g = lane >> 4;
  const int cl = lane & 15;
  const int bid = blockIdx.x;
  const int mode = bid % 3;
  const int rbi  = bid / 3;             // 0..511
  const int rb = rbi << 6;
  const int sr = t >> 3;                // staging: 8 threads per row
  const int sc = t & 7;                 // staging: 16-float chunk index
  const int r1 = rbi & 3;               // superstep rotation
  const int r2 = (rbi >> 2) & 3;        // intra-superstep kf rotation

  const float* Af = (mode == 0) ? Aq : (mode == 1) ? Ak : Av;
  const short8* wp8 = (const short8*)(wpack + (size_t)mode * (512 * 512));

  // physical kf for logical step s (0..15)
  auto kfOf = [&](int s) {
    int sl2 = s >> 2, kl2 = s & 3;
    return (((sl2 + r1) & 3) << 2) + ((kl2 + r2) & 3);
  };

  // ---- prologue: stage physical slice r1; prefetch B steps 0,1 ----
  {
    char* dst = smem + sr * 272 + sc * 32;
    const float* src = Af + (size_t)(rb + sr) * 512 + r1 * 128 + sc * 16;
    f32x4 a0 = *(const f32x4*)(src);
    f32x4 a1 = *(const f32x4*)(src + 4);
    f32x4 a2 = *(const f32x4*)(src + 8);
    f32x4 a3 = *(const f32x4*)(src + 12);
    short8 v0, v1;
#pragma unroll
    for (int j = 0; j < 4; ++j) {
      v0[j] = f2b(a0[j]); v0[4 + j] = f2b(a1[j]);
      v1[j] = f2b(a2[j]); v1[4 + j] = f2b(a3[j]);
    }
    *(short8*)dst = v0; *(short8*)(dst + 16) = v1;
  }
  f32x4 zero4 = {0.f, 0.f, 0.f, 0.f};
  f32x4 acc[4][4];                      // [row-frag][col-frag]
#pragma unroll
  for (int rf = 0; rf < 4; ++rf)
#pragma unroll
    for (int cf = 0; cf < 4; ++cf) acc[rf][cf] = zero4;

  short8 bb[3][4];                      // 2-deep rotating B prefetch
  {
    const int k0 = kfOf(0), k1 = kfOf(1);
#pragma unroll
    for (int cf = 0; cf < 4; ++cf) {
      bb[0][cf] = wp8[((size_t)(k0 * 32 + wid * 4 + cf)) * 64 + lane];
      bb[1][cf] = wp8[((size_t)(k1 * 32 + wid * 4 + cf)) * 64 + lane];
    }
  }
  BAR_LGKM();                           // A slice visible; B prefetch stays in flight

  // ---- main pipeline: 4 logical supersteps of BK=128 (4 kf each) ----
#pragma unroll
  for (int sl = 0; sl < 4; ++sl) {
    const int s_phys = (sl + r1) & 3;
    const int s_next = (s_phys + 1) & 3;
    char* cur = smem + (sl & 1) * 17408;
    f32x4 rA0, rA1, rA2, rA3;           // staged next-slice fp32
    if (sl < 3) {
      const float* src = Af + (size_t)(rb + sr) * 512 + s_next * 128 + sc * 16;
      rA0 = *(const f32x4*)(src);
      rA1 = *(const f32x4*)(src + 4);
      rA2 = *(const f32x4*)(src + 8);
      rA3 = *(const f32x4*)(src + 12);
    }
#pragma unroll
    for (int kl = 0; kl < 4; ++kl) {
      const int s = sl * 4 + kl;        // logical step 0..15
      const int k_phys = (kl + r2) & 3;
      if (s + 2 < 16) {                 // prefetch step s+2 into freed buffer
        const int kf_n = kfOf(s + 2);
#pragma unroll
        for (int cf = 0; cf < 4; ++cf)
          bb[(s + 2) % 3][cf] = wp8[((size_t)(kf_n * 32 + wid * 4 + cf)) * 64 + lane];
      }
      short8 af[4];
#pragma unroll
      for (int rf = 0; rf < 4; ++rf)
        af[rf] = *(const short8*)(cur + (rf * 16 + cl) * 272 + k_phys * 64 + 16 * g);
      __builtin_amdgcn_s_setprio(1);
#pragma unroll
      for (int rf = 0; rf < 4; ++rf)
#pragma unroll
        for (int cf = 0; cf < 4; ++cf)
          acc[rf][cf] = MFMA16x16x32(af[rf], bb[s % 3][cf], acc[rf][cf]);
      __builtin_amdgcn_s_setprio(0);
    }
    if (sl < 3) {
      char* dst = smem + ((sl + 1) & 1) * 17408 + sr * 272 + sc * 32;
      short8 v0, v1;
#pragma unroll
      for (int j = 0; j < 4; ++j) {
        v0[j] = f2b(rA0[j]); v0[4 + j] = f2b(rA1[j]);
        v1[j] = f2b(rA2[j]); v1[4 + j] = f2b(rA3[j]);
      }
      *(short8*)dst = v0; *(short8*)(dst + 16) = v1;
      BAR_LGKM();                       // no vmcnt drain: B prefetch survives
    }
  }

  if (mode < 2) {
    // epilogue: y = (relu(acc)+eps)/softplus(s); row-wise sum(y^2), sum(y^6)
    float sp_inv[4];
#pragma unroll
    for (int cf = 0; cf < 4; ++cf) sp_inv[cf] = 1.f / spls[wid * 64 + cf * 16 + cl];
    float p2[4][4], p6[4][4];
#pragma unroll
    for (int rf = 0; rf < 4; ++rf)
#pragma unroll
      for (int j = 0; j < 4; ++j) { p2[rf][j] = 0.f; p6[rf][j] = 0.f; }
#pragma unroll
    for (int rf = 0; rf < 4; ++rf)
#pragma unroll
      for (int cf = 0; cf < 4; ++cf)
#pragma unroll
        for (int j = 0; j < 4; ++j) {
          float v = acc[rf][cf][j];
          v = fmaxf(v, 0.f) + 1e-6f;
          v *= sp_inv[cf];
          acc[rf][cf][j] = v;
          float v2 = v * v;
          p2[rf][j] += v2;
          p6[rf][j] += v2 * v2 * v2;
        }
    // reduce across the 16 lanes sharing each row (cl bits = lane bits 0..3)
#pragma unroll
    for (int m = 1; m < 16; m <<= 1) {
#pragma unroll
      for (int rf = 0; rf < 4; ++rf)
#pragma unroll
        for (int j = 0; j < 4; ++j) {
          p2[rf][j] += __shfl_xor(p2[rf][j], m, 64);
          p6[rf][j] += __shfl_xor(p6[rf][j], m, 64);
        }
    }
    if (cl == 0) {
#pragma unroll
      for (int rf = 0; rf < 4; ++rf)
#pragma unroll
        for (int j = 0; j < 4; ++j) {
          pnorm[0][wid][rf * 16 + 4 * g + j] = p2[rf][j];
          pnorm[1][wid][rf * 16 + 4 * g + j] = p6[rf][j];
        }
    }
    __syncthreads();
    if (t < 64) {
      float a = 0.f, b = 0.f;
#pragma unroll
      for (int w = 0; w < 8; ++w) { a += pnorm[0][w][t]; b += pnorm[1][w][t]; }
      facs[t] = sqrtf(a / b);           // ||y|| / ||y^3||
    }
    __syncthreads();
    float fac[4][4];
#pragma unroll
    for (int rf = 0; rf < 4; ++rf)
#pragma unroll
      for (int j = 0; j < 4; ++j) fac[rf][j] = facs[rf * 16 + 4 * g + j];
#pragma unroll
    for (int rf = 0; rf < 4; ++rf)
#pragma unroll
      for (int cf = 0; cf < 4; ++cf)
#pragma unroll
        for (int j = 0; j < 4; ++j) {
          float v = acc[rf][cf][j];
          float o = v * v * v * fac[rf][j];
          int r = rf * 16 + 4 * g + j;
          int c = wid * 64 + cf * 16 + cl;
          int byteoff = (r * 1024 + c * 2) ^ ((r & 7) << 4);
          *(short*)((char*)tile + byteoff) = f2b(o);
        }
  } else {
    __syncthreads();                    // A-slice reads must finish before overwrite
#pragma unroll
    for (int rf = 0; rf < 4; ++rf)
#pragma unroll
      for (int cf = 0; cf < 4; ++cf)
#pragma unroll
        for (int j = 0; j < 4; ++j) {
          int r = rf * 16 + 4 * g + j;
          int c = wid * 64 + cf * 16 + cl;
          int byteoff = (r * 1024 + c * 2) ^ ((r & 7) << 4);
          *(short*)((char*)tile + byteoff) = f2b(acc[rf][cf][j]);
        }
  }
  __syncthreads();

  if (mode == 0) {
    // coalesced row-major store
    const int r = t >> 3;
    const int c8 = t & 7;
#pragma unroll
    for (int s = 0; s < 8; ++s) {
      int ci = c8 + 8 * s;
      int byteoff = (r * 1024 + ci * 16) ^ ((r & 7) << 4);
      short8 v = *(const short8*)((const char*)tile + byteoff);
      *(short8*)(qf + (size_t)(rb + r) * 512 + ci * 8) = v;
    }
  } else {
    // k-major fragment pack store
    short* dstp = (mode == 1) ? kpk : vpk;
    const int l = lane;
    const int batch = rb >> 12;
    const int jf_base = (rb & 4095) >> 5;
#pragma unroll
    for (int s = 0; s < 8; ++s) {
      int fidx = wid * 8 + s;           // 0..63 = 2 jfrag x 32 cfrag
      int jf = fidx >> 5;
      int cf = fidx & 31;
      int c = cf * 16 + (l & 15);
      int j0 = jf * 32 + 8 * (l >> 4);
      short8 v;
#pragma unroll
      for (int jj = 0; jj < 8; ++jj) {
        int j = j0 + jj;
        int byteoff = (j * 1024 + c * 2) ^ ((j & 7) << 4);
        v[jj] = *(const short*)((const char*)tile + byteoff);
      }
      int bh = batch * 8 + (cf >> 2);
      int cfh = cf & 3;
      int jfg = jf_base + jf;
      *(short8*)(dstp + (((size_t)(bh * 128 + jfg) * 4 + cfh) * 64 + l) * 8) = v;
    }
  }
}

// ---------------------------------------------------------------------------
// kv: splitK=4 with FUSED final reduction (last-done-block pattern).
// Each block computes its register-accumulated partial and stores it; the
// last block to finish per bh (device-scope atomic counter, all-threads
// threadfence before signal) re-reads the 4 partials in FIXED order and
// emits kvT (bf16) + ksum — bitwise deterministic. Removes the kv_reduce
// dispatch. counters[] zeroed by hipMemsetAsync each launch.
// ---------------------------------------------------------------------------
__global__ __launch_bounds__(256)
void kv_kernel(const short* __restrict__ kpack, const short* __restrict__ vpack,
               float* __restrict__ pKV, float* __restrict__ pKS,
               short* __restrict__ kvT, float* __restrict__ ksum,
               int* __restrict__ counters)
{
  __shared__ float red[4][64 * 64];
  __shared__ float ksacc[64];
  __shared__ int lastFlag;
  const int t = threadIdx.x;
  const int lane = t & 63;
  const int w = t >> 6;
  const int g = lane >> 4;
  const int cl = lane & 15;
  const int bh = blockIdx.x >> 2;
  const int sp = blockIdx.x & 3;
  if (t < 64) ksacc[t] = 0.f;
  __syncthreads();

  f32x4 zero4 = {0.f, 0.f, 0.f, 0.f};
  f32x4 acc[4][4];
#pragma unroll
  for (int df = 0; df < 4; ++df)
#pragma unroll
    for (int cf = 0; cf < 4; ++cf) acc[df][cf] = zero4;
  float ks[4] = {0.f, 0.f, 0.f, 0.f};
  const short8* kp = (const short8*)kpack;
  const short8* vp = (const short8*)vpack;

#pragma unroll
  for (int i = 0; i < 8; ++i) {
    int jfg = sp * 32 + w * 8 + i;
    size_t base = ((size_t)bh * 128 + jfg) * 4 * 64;
    short8 afr[4], bfr[4];
#pragma unroll
    for (int f = 0; f < 4; ++f) {
      afr[f] = vp[base + (size_t)f * 64 + lane];
      bfr[f] = kp[base + (size_t)f * 64 + lane];
    }
#pragma unroll
    for (int cf = 0; cf < 4; ++cf) {
      float s = 0.f;
#pragma unroll
      for (int jj = 0; jj < 8; ++jj) s += b2f(bfr[cf][jj]);
      ks[cf] += s;
    }
#pragma unroll
    for (int df = 0; df < 4; ++df)
#pragma unroll
      for (int cf = 0; cf < 4; ++cf)
        acc[df][cf] = MFMA16x16x32(afr[df], bfr[cf], acc[df][cf]);
  }

#pragma unroll
  for (int cf = 0; cf < 4; ++cf) {
    ks[cf] += __shfl_xor(ks[cf], 16, 64);
    ks[cf] += __shfl_xor(ks[cf], 32, 64);
  }
  if (lane < 16) {
#pragma unroll
    for (int cf = 0; cf < 4; ++cf) atomicAdd(&ksacc[cf * 16 + lane], ks[cf]);
  }

#pragma unroll
  for (int df = 0; df < 4; ++df)
#pragma unroll
    for (int cf = 0; cf < 4; ++cf)
#pragma unroll
      for (int j = 0; j < 4; ++j)
        red[w][(df * 16 + 4 * g + j) * 64 + cf * 16 + cl] = acc[df][cf][j];
  __syncthreads();

  // store this block's fp32 partial
  float* dkv = pKV + (size_t)blockIdx.x * 4096;
  for (int i = t; i < 4096; i += 256)
    dkv[i] = red[0][i] + red[1][i] + red[2][i] + red[3][i];
  if (t < 64) pKS[(size_t)blockIdx.x * 64 + t] = ksacc[t];

  // last-done-block reduction
  __threadfence();                      // each thread: partial stores visible
  __syncthreads();                      // all threads fenced
  if (t == 0) {
    int old = atomicAdd(&counters[bh], 1);
    lastFlag = (old == 3);
  }
  __syncthreads();
  if (lastFlag) {
    __threadfence();                    // acquire: other blocks' partials
    for (int i = t; i < 4096; i += 256) {
      float s = 0.f;
#pragma unroll
      for (int sp2 = 0; sp2 < 4; ++sp2) s += pKV[(size_t)(bh * 4 + sp2) * 4096 + i];
      kvT[(size_t)bh * 4096 + i] = f2b(s);
    }
    if (t < 64) {
      float s = 0.f;
#pragma unroll
      for (int sp2 = 0; sp2 < 4; ++sp2) s += pKS[(size_t)(bh * 4 + sp2) * 64 + t];
      ksum[bh * 64 + t] = s;
    }
  }
}

// ---------------------------------------------------------------------------
// xout: FUSED x + output GEMM (r15/r16). Per block (64 rows):
//  phase 1: z; x = z * q @ kv -> swizzled LDS tile (no HBM round-trip).
//  phase 2: out = x @ Wp + bp from resident LDS; first B batch hoisted early.
// ---------------------------------------------------------------------------
__global__ __launch_bounds__(512, 2)
void xout_kernel(const short* __restrict__ qf, const short* __restrict__ kvT,
                 const float* __restrict__ ksum, const short* __restrict__ wpack,
                 const float* __restrict__ bp, float* __restrict__ out)
{
  __shared__ short xt[64 * 512];
  __shared__ float ksb[512];
  __shared__ float zb[64 * 8];
  const int t = threadIdx.x;
  const int lane = t & 63;
  const int wid = t >> 6;
  const int wr = wid >> 1;
  const int wc = wid & 1;
  const int g = lane >> 4;
  const int cl = lane & 15;
  const int bid = blockIdx.x;
  const int rb = bid << 6;
  const int batch = rb >> 12;
  const int r1 = bid & 3;
  const int r2 = (bid >> 2) & 3;

  // phase-2 first B batch: issue EARLY (hides under phase-1 compute)
  const short8* wp8 = (const short8*)(wpack + (size_t)3 * (512 * 512));
  short8 bcur[4], bnxt[4];
  {
    const int kf0 = (r1 * 4 + r2);
#pragma unroll
    for (int cf = 0; cf < 4; ++cf)
      bcur[cf] = wp8[((size_t)(kf0 * 32 + wid * 4 + cf)) * 64 + lane];
  }

  ksb[t] = ksum[batch * 512 + t];
  __syncthreads();

  // z: one (row, head) pair per thread
  {
    int r = t >> 3, h = t & 7;
    const short8* qrow = (const short8*)(qf + (size_t)(rb + r) * 512 + h * 64);
    float d = 0.f;
#pragma unroll
    for (int c8 = 0; c8 < 8; ++c8) {
      short8 qv = qrow[c8];
#pragma unroll
      for (int jj = 0; jj < 8; ++jj) d += b2f(qv[jj]) * ksb[h * 64 + c8 * 8 + jj];
    }
    zb[r * 8 + h] = 1.f / (d + 1e-6f);
  }
  __syncthreads();

  f32x4 zero4 = {0.f, 0.f, 0.f, 0.f};
  {
    f32x4 xacc[16];
#pragma unroll
    for (int i = 0; i < 16; ++i) xacc[i] = zero4;

    const short8* q8 = (const short8*)qf;
    const size_t qrowbase = (size_t)(rb + wr * 16 + cl) * 64;  // row * 512 / 8
#pragma unroll
    for (int hh = 0; hh < 4; ++hh) {
      int h = wc * 4 + hh;
      short8 af0 = q8[qrowbase + h * 8 + g];
      short8 af1 = q8[qrowbase + h * 8 + 4 + g];
      const short8* kv8 = (const short8*)kvT + ((size_t)(batch * 8 + h)) * 512;
#pragma unroll
      for (int nfl = 0; nfl < 4; ++nfl) {
        short8 b0 = kv8[(size_t)(nfl * 16 + cl) * 8 + g];
        short8 b1 = kv8[(size_t)(nfl * 16 + cl) * 8 + 4 + g];
        int nf = hh * 4 + nfl;
        xacc[nf] = MFMA16x16x32(af0, b0, xacc[nf]);
        xacc[nf] = MFMA16x16x32(af1, b1, xacc[nf]);
      }
    }
    // scale by z and stash x (bf16, swizzled) — stays in LDS
#pragma unroll
    for (int hh = 0; hh < 4; ++hh) {
      int h = wc * 4 + hh;
      float z4[4];
#pragma unroll
      for (int j = 0; j < 4; ++j) z4[j] = zb[(wr * 16 + 4 * g + j) * 8 + h];
#pragma unroll
      for (int nfl = 0; nfl < 4; ++nfl) {
        int nf = hh * 4 + nfl;
#pragma unroll
        for (int j = 0; j < 4; ++j) {
          float xv = xacc[nf][j] * z4[j];
          int r = wr * 16 + 4 * g + j;
          int c = wc * 256 + nf * 16 + cl;
          int byteoff = (r * 1024 + c * 2) ^ ((r & 7) << 4);
          *(short*)((char*)xt + byteoff) = f2b(xv);
        }
      }
    }
  }
  __syncthreads();                      // xt complete, visible to all waves

  // ---- phase 2: out = xt @ Wp + bp (A resident in LDS, no barriers) ----
  f32x4 acc[4][4];
#pragma unroll
  for (int rf = 0; rf < 4; ++rf)
#pragma unroll
    for (int cf = 0; cf < 4; ++cf) acc[rf][cf] = zero4;

#pragma unroll
  for (int sl = 0; sl < 4; ++sl) {
    const int s_phys = (sl + r1) & 3;
#pragma unroll
    for (int kl = 0; kl < 4; ++kl) {
      const int k_phys = (kl + r2) & 3;
      const int kf = s_phys * 4 + k_phys;
      const bool last = (sl == 3) && (kl == 3);
      if (!last) {
        const int kf_n = (kl < 3) ? (s_phys * 4 + ((kl + 1 + r2) & 3))
                                  : (((s_phys + 1) & 3) * 4 + r2);
#pragma unroll
        for (int cf = 0; cf < 4; ++cf)
          bnxt[cf] = wp8[((size_t)(kf_n * 32 + wid * 4 + cf)) * 64 + lane];
      }
      short8 af[4];
#pragma unroll
      for (int rf = 0; rf < 4; ++rf) {
        int row = rf * 16 + cl;
        int byteoff = (row * 1024 + (kf * 32 + 8 * g) * 2) ^ ((row & 7) << 4);
        af[rf] = *(const short8*)((const char*)xt + byteoff);
      }
      __builtin_amdgcn_s_setprio(1);
#pragma unroll
      for (int rf = 0; rf < 4; ++rf)
#pragma unroll
        for (int cf = 0; cf < 4; ++cf)
          acc[rf][cf] = MFMA16x16x32(af[rf], bcur[cf], acc[rf][cf]);
      __builtin_amdgcn_s_setprio(0);
      if (!last) {
#pragma unroll
        for (int cf = 0; cf < 4; ++cf) bcur[cf] = bnxt[cf];
      }
    }
  }

#pragma unroll
  for (int rf = 0; rf < 4; ++rf)
#pragma unroll
    for (int cf = 0; cf < 4; ++cf) {
      int c = wid * 64 + cf * 16 + cl;
      float bv = bp[c];
#pragma unroll
      for (int j = 0; j < 4; ++j)
        out[(size_t)(rb + rf * 16 + 4 * g + j) * 512 + c] = acc[rf][cf][j] + bv;
    }
}

// ---------------------------------------------------------------------------
extern "C" void kernel_launch(void* const* d_in, const int* in_sizes, int n_in,
                              void* d_out, int out_size, void* d_ws, size_t ws_size,
                              hipStream_t stream)
{
  const float* query  = (const float*)d_in[0];
  const float* key_in = (const float*)d_in[1];
  const float* value  = (const float*)d_in[2];
  const float* Wq     = (const float*)d_in[3];
  const float* Wk     = (const float*)d_in[4];
  const float* Wv     = (const float*)d_in[5];
  const float* Wp     = (const float*)d_in[6];
  const float* bp     = (const float*)d_in[7];
  const float* scale  = (const float*)d_in[8];
  float* out = (float*)d_out;

  char* ws = (char*)d_ws;
  size_t off = 0;
  auto alloc = [&](size_t bytes) -> void* {
    void* p = ws + off;
    off += (bytes + 255) & ~(size_t)255;
    return p;
  };
  float* spls  = (float*)alloc(512 * 4);
  short* wpack = (short*)alloc((size_t)4 * 512 * 512 * 2);
  short* qf    = (short*)alloc((size_t)32768 * 512 * 2);
  short* kpack = (short*)alloc((size_t)32768 * 512 * 2);
  short* vpack = (short*)alloc((size_t)32768 * 512 * 2);
  float* pKV   = (float*)alloc((size_t)256 * 4096 * 4);
  float* pKS   = (float*)alloc((size_t)256 * 64 * 4);
  short* kvT   = (short*)alloc((size_t)64 * 4096 * 2);
  float* ksum  = (float*)alloc((size_t)64 * 64 * 4);
  int*   ctrs  = (int*)alloc((size_t)64 * 4);

  prep_kernel<<<65, 256, 0, stream>>>(Wq, Wk, Wv, Wp, scale, wpack, spls);
  (void)hipMemsetAsync(ctrs, 0, (size_t)64 * 4, stream);
  proj_kernel<<<1536, 512, 0, stream>>>(query, key_in, value, wpack, spls,
                                        qf, kpack, vpack);
  kv_kernel<<<256, 256, 0, stream>>>(kpack, vpack, pKV, pKS, kvT, ksum, ctrs);
  xout_kernel<<<512, 512, 0, stream>>>(qf, kvT, ksum, wpack, bp, out);
}

// Round 20
// 175.763 us; speedup vs baseline: 1.1749x; 1.1749x over previous
//
#include <hip/hip_runtime.h>
#include <hip/hip_bf16.h>
#include <math.h>

typedef __attribute__((ext_vector_type(8))) short short8;   // 8 bf16 = one MFMA A/B frag
typedef __attribute__((ext_vector_type(4))) float f32x4;    // MFMA C/D frag

#define MFMA16x16x32(A,B,C) __builtin_amdgcn_mfma_f32_16x16x32_bf16((A),(B),(C),0,0,0)
#define LGKM0()   asm volatile("s_waitcnt lgkmcnt(0)" ::: "memory")
// barrier that does NOT drain vmcnt (keeps B/A register prefetches in flight)
#define BAR_LGKM() do { LGKM0(); __builtin_amdgcn_s_barrier(); } while (0)

__device__ __forceinline__ short f2b(float x) {
  __hip_bfloat16 h = __float2bfloat16(x);
  short s; __builtin_memcpy(&s, &h, 2); return s;
}
__device__ __forceinline__ float b2f(short s) {
  __hip_bfloat16 h; __builtin_memcpy(&h, &s, 2); return __bfloat162float(h);
}

// ---------------------------------------------------------------------------
// prep: blocks 0..63 pack the 4 weights [512][512] fp32 -> bf16 MFMA B-frag
// order: elem index = ((kf*32 + nf)*64 + lane)*8 + jj, where lane holds
// (n = nf*16 + lane%16, k = kf*32 + 8*(lane/16) + jj). block 64: softplus(scale).
// ---------------------------------------------------------------------------
__global__ __launch_bounds__(256)
void prep_kernel(const float* __restrict__ Wq, const float* __restrict__ Wk,
                 const float* __restrict__ Wv, const float* __restrict__ Wp,
                 const float* __restrict__ scale,
                 short* __restrict__ wpack, float* __restrict__ spls)
{
  const int b = blockIdx.x;
  const int t = threadIdx.x;
  if (b == 64) {
    for (int i = t; i < 512; i += 256) {
      float x = scale[i];
      spls[i] = (x > 20.f) ? x : log1pf(expf(x));
    }
    return;
  }
  const float* Ws[4] = {Wq, Wk, Wv, Wp};
  const int w = b >> 4, kf16 = b & 15;
  const float* W = Ws[w];
  short* dst = wpack + (size_t)w * (512 * 512);
  __shared__ short lds[32 * 512];
  for (int i = 0; i < 64; ++i) {
    int idx = i * 256 + t;              // 0..16383
    int r = idx >> 9, c = idx & 511;
    lds[idx] = f2b(W[(size_t)(kf16 * 32 + r) * 512 + c]);
  }
  __syncthreads();
  for (int s = 0; s < 8; ++s) {
    int slot = s * 256 + t;             // 0..2047 = 32 nfrags x 64 lanes
    int nf = slot >> 6, l = slot & 63;
    int n = nf * 16 + (l & 15);
    int k0 = 8 * (l >> 4);
    short8 v;
#pragma unroll
    for (int jj = 0; jj < 8; ++jj) v[jj] = lds[(k0 + jj) * 512 + n];
    *(short8*)(dst + ((size_t)(kf16 * 32 + nf) * 64 + l) * 8) = v;
  }
}

// ---------------------------------------------------------------------------
// proj (r18 best): fused q/k/v, 64 rows x 512 cols, 8 waves, 4x4 acc,
// A-slice dbuf BK=128 padded LDS, 2-deep rotating B reg prefetch, per-block
// kf phase rotation, lgkm-only barriers, mode=bid%3 interleave, setprio.
// mode 0: q -> relu,+eps,/s,focus -> row-major bf16.
// mode 1: k -> same epilogue -> k-major frag pack. mode 2: v -> plain pack.
// ---------------------------------------------------------------------------
__global__ __launch_bounds__(512, 2)
void proj_kernel(const float* __restrict__ Aq, const float* __restrict__ Ak,
                 const float* __restrict__ Av,
                 const short* __restrict__ wpack, const float* __restrict__ spls,
                 short* __restrict__ qf, short* __restrict__ kpk,
                 short* __restrict__ vpk)
{
  __shared__ char smem[65536];          // A-slice dbuf (2x17408B) / 64KB bounce
  __shared__ float pnorm[2][8][64];     // per-wave row-norm partials
  __shared__ float facs[64];
  short* tile = (short*)smem;
  const int t = threadIdx.x;
  const int lane = t & 63;
  const int wid = t >> 6;               // wave owns cols [wid*64, wid*64+64)
  const int g = lane >> 4;
  const int cl = lane & 15;
  const int bid = blockIdx.x;
  const int mode = bid % 3;
  const int rbi  = bid / 3;             // 0..511
  const int rb = rbi << 6;
  const int sr = t >> 3;                // staging: 8 threads per row
  const int sc = t & 7;                 // staging: 16-float chunk index
  const int r1 = rbi & 3;               // superstep rotation
  const int r2 = (rbi >> 2) & 3;        // intra-superstep kf rotation

  const float* Af = (mode == 0) ? Aq : (mode == 1) ? Ak : Av;
  const short8* wp8 = (const short8*)(wpack + (size_t)mode * (512 * 512));

  // physical kf for logical step s (0..15)
  auto kfOf = [&](int s) {
    int sl2 = s >> 2, kl2 = s & 3;
    return (((sl2 + r1) & 3) << 2) + ((kl2 + r2) & 3);
  };

  // ---- prologue: stage physical slice r1; prefetch B steps 0,1 ----
  {
    char* dst = smem + sr * 272 + sc * 32;
    const float* src = Af + (size_t)(rb + sr) * 512 + r1 * 128 + sc * 16;
    f32x4 a0 = *(const f32x4*)(src);
    f32x4 a1 = *(const f32x4*)(src + 4);
    f32x4 a2 = *(const f32x4*)(src + 8);
    f32x4 a3 = *(const f32x4*)(src + 12);
    short8 v0, v1;
#pragma unroll
    for (int j = 0; j < 4; ++j) {
      v0[j] = f2b(a0[j]); v0[4 + j] = f2b(a1[j]);
      v1[j] = f2b(a2[j]); v1[4 + j] = f2b(a3[j]);
    }
    *(short8*)dst = v0; *(short8*)(dst + 16) = v1;
  }
  f32x4 zero4 = {0.f, 0.f, 0.f, 0.f};
  f32x4 acc[4][4];                      // [row-frag][col-frag]
#pragma unroll
  for (int rf = 0; rf < 4; ++rf)
#pragma unroll
    for (int cf = 0; cf < 4; ++cf) acc[rf][cf] = zero4;

  short8 bb[3][4];                      // 2-deep rotating B prefetch
  {
    const int k0 = kfOf(0), k1 = kfOf(1);
#pragma unroll
    for (int cf = 0; cf < 4; ++cf) {
      bb[0][cf] = wp8[((size_t)(k0 * 32 + wid * 4 + cf)) * 64 + lane];
      bb[1][cf] = wp8[((size_t)(k1 * 32 + wid * 4 + cf)) * 64 + lane];
    }
  }
  BAR_LGKM();                           // A slice visible; B prefetch stays in flight

  // ---- main pipeline: 4 logical supersteps of BK=128 (4 kf each) ----
#pragma unroll
  for (int sl = 0; sl < 4; ++sl) {
    const int s_phys = (sl + r1) & 3;
    const int s_next = (s_phys + 1) & 3;
    char* cur = smem + (sl & 1) * 17408;
    f32x4 rA0, rA1, rA2, rA3;           // staged next-slice fp32
    if (sl < 3) {
      const float* src = Af + (size_t)(rb + sr) * 512 + s_next * 128 + sc * 16;
      rA0 = *(const f32x4*)(src);
      rA1 = *(const f32x4*)(src + 4);
      rA2 = *(const f32x4*)(src + 8);
      rA3 = *(const f32x4*)(src + 12);
    }
#pragma unroll
    for (int kl = 0; kl < 4; ++kl) {
      const int s = sl * 4 + kl;        // logical step 0..15
      const int k_phys = (kl + r2) & 3;
      if (s + 2 < 16) {                 // prefetch step s+2 into freed buffer
        const int kf_n = kfOf(s + 2);
#pragma unroll
        for (int cf = 0; cf < 4; ++cf)
          bb[(s + 2) % 3][cf] = wp8[((size_t)(kf_n * 32 + wid * 4 + cf)) * 64 + lane];
      }
      short8 af[4];
#pragma unroll
      for (int rf = 0; rf < 4; ++rf)
        af[rf] = *(const short8*)(cur + (rf * 16 + cl) * 272 + k_phys * 64 + 16 * g);
      __builtin_amdgcn_s_setprio(1);
#pragma unroll
      for (int rf = 0; rf < 4; ++rf)
#pragma unroll
        for (int cf = 0; cf < 4; ++cf)
          acc[rf][cf] = MFMA16x16x32(af[rf], bb[s % 3][cf], acc[rf][cf]);
      __builtin_amdgcn_s_setprio(0);
    }
    if (sl < 3) {
      char* dst = smem + ((sl + 1) & 1) * 17408 + sr * 272 + sc * 32;
      short8 v0, v1;
#pragma unroll
      for (int j = 0; j < 4; ++j) {
        v0[j] = f2b(rA0[j]); v0[4 + j] = f2b(rA1[j]);
        v1[j] = f2b(rA2[j]); v1[4 + j] = f2b(rA3[j]);
      }
      *(short8*)dst = v0; *(short8*)(dst + 16) = v1;
      BAR_LGKM();                       // no vmcnt drain: B prefetch survives
    }
  }

  if (mode < 2) {
    // epilogue: y = (relu(acc)+eps)/softplus(s); row-wise sum(y^2), sum(y^6)
    float sp_inv[4];
#pragma unroll
    for (int cf = 0; cf < 4; ++cf) sp_inv[cf] = 1.f / spls[wid * 64 + cf * 16 + cl];
    float p2[4][4], p6[4][4];
#pragma unroll
    for (int rf = 0; rf < 4; ++rf)
#pragma unroll
      for (int j = 0; j < 4; ++j) { p2[rf][j] = 0.f; p6[rf][j] = 0.f; }
#pragma unroll
    for (int rf = 0; rf < 4; ++rf)
#pragma unroll
      for (int cf = 0; cf < 4; ++cf)
#pragma unroll
        for (int j = 0; j < 4; ++j) {
          float v = acc[rf][cf][j];
          v = fmaxf(v, 0.f) + 1e-6f;
          v *= sp_inv[cf];
          acc[rf][cf][j] = v;
          float v2 = v * v;
          p2[rf][j] += v2;
          p6[rf][j] += v2 * v2 * v2;
        }
    // reduce across the 16 lanes sharing each row (cl bits = lane bits 0..3)
#pragma unroll
    for (int m = 1; m < 16; m <<= 1) {
#pragma unroll
      for (int rf = 0; rf < 4; ++rf)
#pragma unroll
        for (int j = 0; j < 4; ++j) {
          p2[rf][j] += __shfl_xor(p2[rf][j], m, 64);
          p6[rf][j] += __shfl_xor(p6[rf][j], m, 64);
        }
    }
    if (cl == 0) {
#pragma unroll
      for (int rf = 0; rf < 4; ++rf)
#pragma unroll
        for (int j = 0; j < 4; ++j) {
          pnorm[0][wid][rf * 16 + 4 * g + j] = p2[rf][j];
          pnorm[1][wid][rf * 16 + 4 * g + j] = p6[rf][j];
        }
    }
    __syncthreads();
    if (t < 64) {
      float a = 0.f, b = 0.f;
#pragma unroll
      for (int w = 0; w < 8; ++w) { a += pnorm[0][w][t]; b += pnorm[1][w][t]; }
      facs[t] = sqrtf(a / b);           // ||y|| / ||y^3||
    }
    __syncthreads();
    float fac[4][4];
#pragma unroll
    for (int rf = 0; rf < 4; ++rf)
#pragma unroll
      for (int j = 0; j < 4; ++j) fac[rf][j] = facs[rf * 16 + 4 * g + j];
#pragma unroll
    for (int rf = 0; rf < 4; ++rf)
#pragma unroll
      for (int cf = 0; cf < 4; ++cf)
#pragma unroll
        for (int j = 0; j < 4; ++j) {
          float v = acc[rf][cf][j];
          float o = v * v * v * fac[rf][j];
          int r = rf * 16 + 4 * g + j;
          int c = wid * 64 + cf * 16 + cl;
          int byteoff = (r * 1024 + c * 2) ^ ((r & 7) << 4);
          *(short*)((char*)tile + byteoff) = f2b(o);
        }
  } else {
    __syncthreads();                    // A-slice reads must finish before overwrite
#pragma unroll
    for (int rf = 0; rf < 4; ++rf)
#pragma unroll
      for (int cf = 0; cf < 4; ++cf)
#pragma unroll
        for (int j = 0; j < 4; ++j) {
          int r = rf * 16 + 4 * g + j;
          int c = wid * 64 + cf * 16 + cl;
          int byteoff = (r * 1024 + c * 2) ^ ((r & 7) << 4);
          *(short*)((char*)tile + byteoff) = f2b(acc[rf][cf][j]);
        }
  }
  __syncthreads();

  if (mode == 0) {
    // coalesced row-major store
    const int r = t >> 3;
    const int c8 = t & 7;
#pragma unroll
    for (int s = 0; s < 8; ++s) {
      int ci = c8 + 8 * s;
      int byteoff = (r * 1024 + ci * 16) ^ ((r & 7) << 4);
      short8 v = *(const short8*)((const char*)tile + byteoff);
      *(short8*)(qf + (size_t)(rb + r) * 512 + ci * 8) = v;
    }
  } else {
    // k-major fragment pack store
    short* dstp = (mode == 1) ? kpk : vpk;
    const int l = lane;
    const int batch = rb >> 12;
    const int jf_base = (rb & 4095) >> 5;
#pragma unroll
    for (int s = 0; s < 8; ++s) {
      int fidx = wid * 8 + s;           // 0..63 = 2 jfrag x 32 cfrag
      int jf = fidx >> 5;
      int cf = fidx & 31;
      int c = cf * 16 + (l & 15);
      int j0 = jf * 32 + 8 * (l >> 4);
      short8 v;
#pragma unroll
      for (int jj = 0; jj < 8; ++jj) {
        int j = j0 + jj;
        int byteoff = (j * 1024 + c * 2) ^ ((j & 7) << 4);
        v[jj] = *(const short*)((const char*)tile + byteoff);
      }
      int bh = batch * 8 + (cf >> 2);
      int cfh = cf & 3;
      int jfg = jf_base + jf;
      *(short8*)(dstp + (((size_t)(bh * 128 + jfg) * 4 + cfh) * 64 + l) * 8) = v;
    }
  }
}

// ---------------------------------------------------------------------------
// kv: splitK=4: block = (bh, quarter of 1024 tokens); 4 waves x 8 jfg chunks
// each, register-accumulated; cross-wave LDS reduce; one fp32 partial/block.
// ---------------------------------------------------------------------------
__global__ __launch_bounds__(256)
void kv_kernel(const short* __restrict__ kpack, const short* __restrict__ vpack,
               float* __restrict__ pKV, float* __restrict__ pKS)
{
  __shared__ float red[4][64 * 64];
  __shared__ float ksacc[64];
  const int t = threadIdx.x;
  const int lane = t & 63;
  const int w = t >> 6;
  const int g = lane >> 4;
  const int cl = lane & 15;
  const int bh = blockIdx.x >> 2;
  const int sp = blockIdx.x & 3;
  if (t < 64) ksacc[t] = 0.f;
  __syncthreads();

  f32x4 zero4 = {0.f, 0.f, 0.f, 0.f};
  f32x4 acc[4][4];
#pragma unroll
  for (int df = 0; df < 4; ++df)
#pragma unroll
    for (int cf = 0; cf < 4; ++cf) acc[df][cf] = zero4;
  float ks[4] = {0.f, 0.f, 0.f, 0.f};
  const short8* kp = (const short8*)kpack;
  const short8* vp = (const short8*)vpack;

#pragma unroll
  for (int i = 0; i < 8; ++i) {
    int jfg = sp * 32 + w * 8 + i;
    size_t base = ((size_t)bh * 128 + jfg) * 4 * 64;
    short8 afr[4], bfr[4];
#pragma unroll
    for (int f = 0; f < 4; ++f) {
      afr[f] = vp[base + (size_t)f * 64 + lane];
      bfr[f] = kp[base + (size_t)f * 64 + lane];
    }
#pragma unroll
    for (int cf = 0; cf < 4; ++cf) {
      float s = 0.f;
#pragma unroll
      for (int jj = 0; jj < 8; ++jj) s += b2f(bfr[cf][jj]);
      ks[cf] += s;
    }
#pragma unroll
    for (int df = 0; df < 4; ++df)
#pragma unroll
      for (int cf = 0; cf < 4; ++cf)
        acc[df][cf] = MFMA16x16x32(afr[df], bfr[cf], acc[df][cf]);
  }

#pragma unroll
  for (int cf = 0; cf < 4; ++cf) {
    ks[cf] += __shfl_xor(ks[cf], 16, 64);
    ks[cf] += __shfl_xor(ks[cf], 32, 64);
  }
  if (lane < 16) {
#pragma unroll
    for (int cf = 0; cf < 4; ++cf) atomicAdd(&ksacc[cf * 16 + lane], ks[cf]);
  }

#pragma unroll
  for (int df = 0; df < 4; ++df)
#pragma unroll
    for (int cf = 0; cf < 4; ++cf)
#pragma unroll
      for (int j = 0; j < 4; ++j)
        red[w][(df * 16 + 4 * g + j) * 64 + cf * 16 + cl] = acc[df][cf][j];
  __syncthreads();

  float* dkv = pKV + (size_t)blockIdx.x * 4096;
  for (int i = t; i < 4096; i += 256)
    dkv[i] = red[0][i] + red[1][i] + red[2][i] + red[3][i];
  if (t < 64) pKS[(size_t)blockIdx.x * 64 + t] = ksacc[t];
}

__global__ __launch_bounds__(256)
void kv_reduce(const float* __restrict__ pKV, const float* __restrict__ pKS,
               short* __restrict__ kvT, float* __restrict__ ksum)
{
  const int bh = blockIdx.x;
  const int t = threadIdx.x;
  for (int i = t; i < 4096; i += 256) {
    float s = 0.f;
#pragma unroll
    for (int sp = 0; sp < 4; ++sp) s += pKV[(size_t)(bh * 4 + sp) * 4096 + i];
    kvT[(size_t)bh * 4096 + i] = f2b(s);
  }
  if (t < 64) {
    float s = 0.f;
#pragma unroll
    for (int sp = 0; sp < 4; ++sp) s += pKS[(size_t)(bh * 4 + sp) * 64 + t];
    ksum[bh * 64 + t] = s;
  }
}

// ---------------------------------------------------------------------------
// xout: FUSED x + output GEMM (r15/r16). Per block (64 rows):
//  phase 1: z; x = z * q @ kv -> swizzled LDS tile (no HBM round-trip).
//  phase 2: out = x @ Wp + bp from resident LDS; first B batch hoisted early.
// ---------------------------------------------------------------------------
__global__ __launch_bounds__(512, 2)
void xout_kernel(const short* __restrict__ qf, const short* __restrict__ kvT,
                 const float* __restrict__ ksum, const short* __restrict__ wpack,
                 const float* __restrict__ bp, float* __restrict__ out)
{
  __shared__ short xt[64 * 512];
  __shared__ float ksb[512];
  __shared__ float zb[64 * 8];
  const int t = threadIdx.x;
  const int lane = t & 63;
  const int wid = t >> 6;
  const int wr = wid >> 1;
  const int wc = wid & 1;
  const int g = lane >> 4;
  const int cl = lane & 15;
  const int bid = blockIdx.x;
  const int rb = bid << 6;
  const int batch = rb >> 12;
  const int r1 = bid & 3;
  const int r2 = (bid >> 2) & 3;

  // phase-2 first B batch: issue EARLY (hides under phase-1 compute)
  const short8* wp8 = (const short8*)(wpack + (size_t)3 * (512 * 512));
  short8 bcur[4], bnxt[4];
  {
    const int kf0 = (r1 * 4 + r2);
#pragma unroll
    for (int cf = 0; cf < 4; ++cf)
      bcur[cf] = wp8[((size_t)(kf0 * 32 + wid * 4 + cf)) * 64 + lane];
  }

  ksb[t] = ksum[batch * 512 + t];
  __syncthreads();

  // z: one (row, head) pair per thread
  {
    int r = t >> 3, h = t & 7;
    const short8* qrow = (const short8*)(qf + (size_t)(rb + r) * 512 + h * 64);
    float d = 0.f;
#pragma unroll
    for (int c8 = 0; c8 < 8; ++c8) {
      short8 qv = qrow[c8];
#pragma unroll
      for (int jj = 0; jj < 8; ++jj) d += b2f(qv[jj]) * ksb[h * 64 + c8 * 8 + jj];
    }
    zb[r * 8 + h] = 1.f / (d + 1e-6f);
  }
  __syncthreads();

  f32x4 zero4 = {0.f, 0.f, 0.f, 0.f};
  {
    f32x4 xacc[16];
#pragma unroll
    for (int i = 0; i < 16; ++i) xacc[i] = zero4;

    const short8* q8 = (const short8*)qf;
    const size_t qrowbase = (size_t)(rb + wr * 16 + cl) * 64;  // row * 512 / 8
#pragma unroll
    for (int hh = 0; hh < 4; ++hh) {
      int h = wc * 4 + hh;
      short8 af0 = q8[qrowbase + h * 8 + g];
      short8 af1 = q8[qrowbase + h * 8 + 4 + g];
      const short8* kv8 = (const short8*)kvT + ((size_t)(batch * 8 + h)) * 512;
#pragma unroll
      for (int nfl = 0; nfl < 4; ++nfl) {
        short8 b0 = kv8[(size_t)(nfl * 16 + cl) * 8 + g];
        short8 b1 = kv8[(size_t)(nfl * 16 + cl) * 8 + 4 + g];
        int nf = hh * 4 + nfl;
        xacc[nf] = MFMA16x16x32(af0, b0, xacc[nf]);
        xacc[nf] = MFMA16x16x32(af1, b1, xacc[nf]);
      }
    }
    // scale by z and stash x (bf16, swizzled) — stays in LDS
#pragma unroll
    for (int hh = 0; hh < 4; ++hh) {
      int h = wc * 4 + hh;
      float z4[4];
#pragma unroll
      for (int j = 0; j < 4; ++j) z4[j] = zb[(wr * 16 + 4 * g + j) * 8 + h];
#pragma unroll
      for (int nfl = 0; nfl < 4; ++nfl) {
        int nf = hh * 4 + nfl;
#pragma unroll
        for (int j = 0; j < 4; ++j) {
          float xv = xacc[nf][j] * z4[j];
          int r = wr * 16 + 4 * g + j;
          int c = wc * 256 + nf * 16 + cl;
          int byteoff = (r * 1024 + c * 2) ^ ((r & 7) << 4);
          *(short*)((char*)xt + byteoff) = f2b(xv);
        }
      }
    }
  }
  __syncthreads();                      // xt complete, visible to all waves

  // ---- phase 2: out = xt @ Wp + bp (A resident in LDS, no barriers) ----
  f32x4 acc[4][4];
#pragma unroll
  for (int rf = 0; rf < 4; ++rf)
#pragma unroll
    for (int cf = 0; cf < 4; ++cf) acc[rf][cf] = zero4;

#pragma unroll
  for (int sl = 0; sl < 4; ++sl) {
    const int s_phys = (sl + r1) & 3;
#pragma unroll
    for (int kl = 0; kl < 4; ++kl) {
      const int k_phys = (kl + r2) & 3;
      const int kf = s_phys * 4 + k_phys;
      const bool last = (sl == 3) && (kl == 3);
      if (!last) {
        const int kf_n = (kl < 3) ? (s_phys * 4 + ((kl + 1 + r2) & 3))
                                  : (((s_phys + 1) & 3) * 4 + r2);
#pragma unroll
        for (int cf = 0; cf < 4; ++cf)
          bnxt[cf] = wp8[((size_t)(kf_n * 32 + wid * 4 + cf)) * 64 + lane];
      }
      short8 af[4];
#pragma unroll
      for (int rf = 0; rf < 4; ++rf) {
        int row = rf * 16 + cl;
        int byteoff = (row * 1024 + (kf * 32 + 8 * g) * 2) ^ ((row & 7) << 4);
        af[rf] = *(const short8*)((const char*)xt + byteoff);
      }
      __builtin_amdgcn_s_setprio(1);
#pragma unroll
      for (int rf = 0; rf < 4; ++rf)
#pragma unroll
        for (int cf = 0; cf < 4; ++cf)
          acc[rf][cf] = MFMA16x16x32(af[rf], bcur[cf], acc[rf][cf]);
      __builtin_amdgcn_s_setprio(0);
      if (!last) {
#pragma unroll
        for (int cf = 0; cf < 4; ++cf) bcur[cf] = bnxt[cf];
      }
    }
  }

#pragma unroll
  for (int rf = 0; rf < 4; ++rf)
#pragma unroll
    for (int cf = 0; cf < 4; ++cf) {
      int c = wid * 64 + cf * 16 + cl;
      float bv = bp[c];
#pragma unroll
      for (int j = 0; j < 4; ++j)
        out[(size_t)(rb + rf * 16 + 4 * g + j) * 512 + c] = acc[rf][cf][j] + bv;
    }
}

// ---------------------------------------------------------------------------
extern "C" void kernel_launch(void* const* d_in, const int* in_sizes, int n_in,
                              void* d_out, int out_size, void* d_ws, size_t ws_size,
                              hipStream_t stream)
{
  const float* query  = (const float*)d_in[0];
  const float* key_in = (const float*)d_in[1];
  const float* value  = (const float*)d_in[2];
  const float* Wq     = (const float*)d_in[3];
  const float* Wk     = (const float*)d_in[4];
  const float* Wv     = (const float*)d_in[5];
  const float* Wp     = (const float*)d_in[6];
  const float* bp     = (const float*)d_in[7];
  const float* scale  = (const float*)d_in[8];
  float* out = (float*)d_out;

  char* ws = (char*)d_ws;
  size_t off = 0;
  auto alloc = [&](size_t bytes) -> void* {
    void* p = ws + off;
    off += (bytes + 255) & ~(size_t)255;
    return p;
  };
  float* spls  = (float*)alloc(512 * 4);
  short* wpack = (short*)alloc((size_t)4 * 512 * 512 * 2);
  short* qf    = (short*)alloc((size_t)32768 * 512 * 2);
  short* kpack = (short*)alloc((size_t)32768 * 512 * 2);
  short* vpack = (short*)alloc((size_t)32768 * 512 * 2);
  float* pKV   = (float*)alloc((size_t)256 * 4096 * 4);
  float* pKS   = (float*)alloc((size_t)256 * 64 * 4);
  short* kvT   = (short*)alloc((size_t)64 * 4096 * 2);
  float* ksum  = (float*)alloc((size_t)64 * 64 * 4);

  prep_kernel<<<65, 256, 0, stream>>>(Wq, Wk, Wv, Wp, scale, wpack, spls);
  proj_kernel<<<1536, 512, 0, stream>>>(query, key_in, value, wpack, spls,
                                        qf, kpack, vpack);
  kv_kernel<<<256, 256, 0, stream>>>(kpack, vpack, pKV, pKS);
  kv_reduce<<<64, 256, 0, stream>>>(pKV, pKS, kvT, ksum);
  xout_kernel<<<512, 512, 0, stream>>>(qf, kvT, ksum, wpack, bp, out);
}